// Round 6
// baseline (337.993 us; speedup 1.0000x reference)
//
#include <hip/hip_runtime.h>
#include <hip/hip_bf16.h>

typedef __bf16 bf16x8_t __attribute__((ext_vector_type(8)));
typedef __bf16 bf16x4_t __attribute__((ext_vector_type(4)));
typedef float  f32x4_t  __attribute__((ext_vector_type(4)));

#define MFMA_16x16x32_BF16(A, B, C) __builtin_amdgcn_mfma_f32_16x16x32_bf16((A), (B), (C), 0, 0, 0)

static constexpr int B_ = 16;
static constexpr int T_ = 2048;
static constexpr int C_ = 1024;
static constexpr int H_ = 128;
static constexpr long M_ = (long)B_ * T_;   // 32768 rows

// ---------------------------------------------------------------------------
// W transpose: WT[z][h][c] = bf16(W_z[c][h]).  Flat: WT[n][c], n = z*128+h.
// 786 KB -> L2-resident in every XCD; proj reads B-fragments from it directly.
// ---------------------------------------------------------------------------
__global__ __launch_bounds__(128) void wt_kernel(
    const float* __restrict__ Wq, const float* __restrict__ Wk,
    const float* __restrict__ Wv, __bf16* __restrict__ WT)
{
    const int z = blockIdx.y;
    const float* __restrict__ W = (z == 0) ? Wq : (z == 1) ? Wk : Wv;
    const int h  = threadIdx.x;
    const int c0 = blockIdx.x * 8;
    bf16x8_t v;
    #pragma unroll
    for (int j = 0; j < 8; ++j)
        v[j] = (__bf16)W[(c0 + j) * H_ + h];
    *(bf16x8_t*)&WT[((long)z * H_ + h) * C_ + c0] = v;
}

// ---------------------------------------------------------------------------
// Fused projection, v2: NO WT staging. B-fragments read directly from global
// WT (L2-hot); only the 32x32 x-tile goes through LDS, double-buffered with
// ONE barrier per k-step; next x-tile load issued before the MFMA block.
// Grid 1024 x 256 thr: block = 32 rows; wave w owns n-tiles 6w..6w+5
// (x2 m-tiles = 12 MFMA/k-step, acc 48 VGPR). ~4 blocks/CU.
// ---------------------------------------------------------------------------
__global__ __launch_bounds__(256) void proj_kernel(
    const float*  __restrict__ x,
    const __bf16* __restrict__ WT,
    __bf16* __restrict__ qo,
    __bf16* __restrict__ ko,
    __bf16* __restrict__ vo)
{
    __shared__ __bf16 XS[2][32 * 40];   // [row][k], stride 40, double-buffered (5 KB)

    const int tid  = threadIdx.x;
    const int lane = tid & 63;
    const int w    = tid >> 6;
    const int m16  = lane & 15;
    const int quad = lane >> 4;
    const int koff = quad * 8;

    const long r0 = (long)blockIdx.x * 32;
    const int xrow = tid >> 3, xc4 = tid & 7;    // x staging coords (16B fp32/thread)

    f32x4_t acc[2][6];
    #pragma unroll
    for (int mt = 0; mt < 2; ++mt)
        #pragma unroll
        for (int nt = 0; nt < 6; ++nt)
            acc[mt][nt] = f32x4_t{0, 0, 0, 0};

    // stage k0 = 0
    {
        f32x4_t xv = *(const f32x4_t*)&x[(r0 + xrow) * C_ + xc4 * 4];
        bf16x4_t xb;
        #pragma unroll
        for (int j = 0; j < 4; ++j) xb[j] = (__bf16)xv[j];
        *(bf16x4_t*)&XS[0][xrow * 40 + xc4 * 4] = xb;
    }
    __syncthreads();

    for (int k0 = 0; k0 < C_; k0 += 32) {
        const int par = (k0 >> 5) & 1;
        const bool more = (k0 + 32 < C_);

        // issue next x-tile load early (completes during MFMAs)
        f32x4_t xv;
        if (more)
            xv = *(const f32x4_t*)&x[(r0 + xrow) * C_ + k0 + 32 + xc4 * 4];

        // A-fragments from LDS
        bf16x8_t a0 = *(const bf16x8_t*)&XS[par][m16 * 40 + koff];
        bf16x8_t a1 = *(const bf16x8_t*)&XS[par][(16 + m16) * 40 + koff];

        // B-fragments direct from global WT (row n = ntg*16+m16, 16B each)
        #pragma unroll
        for (int nt = 0; nt < 6; ++nt) {
            const int ntg = w * 6 + nt;
            bf16x8_t bfr = *(const bf16x8_t*)&WT[(long)(ntg * 16 + m16) * C_ + k0 + koff];
            acc[0][nt] = MFMA_16x16x32_BF16(a0, bfr, acc[0][nt]);
            acc[1][nt] = MFMA_16x16x32_BF16(a1, bfr, acc[1][nt]);
        }

        // convert + write next x-tile into the other buffer
        if (more) {
            bf16x4_t xb;
            #pragma unroll
            for (int j = 0; j < 4; ++j) xb[j] = (__bf16)xv[j];
            *(bf16x4_t*)&XS[par ^ 1][xrow * 40 + xc4 * 4] = xb;
        }
        __syncthreads();
    }

    // Epilogue. C/D: col = m16 (n), row = quad*4 + r (m).
    #pragma unroll
    for (int mt = 0; mt < 2; ++mt) {
        const long rbase = r0 + mt * 16 + quad * 4;
        #pragma unroll
        for (int nt = 0; nt < 6; ++nt) {
            const int ntg = w * 6 + nt;
            const int z = ntg >> 3;
            const int h = (ntg & 7) * 16 + m16;
            if (z < 2) {
                __bf16* __restrict__ o = z ? ko : qo;
                #pragma unroll
                for (int r = 0; r < 4; ++r)
                    o[(rbase + r) * H_ + h] = (__bf16)acc[mt][nt][r];
            } else {
                long bb = rbase >> 11, tt = rbase & 2047;   // 32 | 2048
                bf16x4_t pk;
                #pragma unroll
                for (int r = 0; r < 4; ++r) pk[r] = (__bf16)acc[mt][nt][r];
                *(bf16x4_t*)&vo[bb * (H_ * (long)T_) + h * (long)T_ + tt] = pk;
            }
        }
    }
}

// ---------------------------------------------------------------------------
// Flash attention, causal, transposed-score, LDS-shared K/V + REGISTER
// PIPELINE: tile t+1's global loads are issued right after the tiles-ready
// barrier and land in registers while tile t's 32 MFMAs + softmax run;
// the next iteration only pays the (completed) vmcnt + LDS write.
// Block = 4 waves x 16 q-rows; grid 512 1-D, batch = L&15 (XCD-pins K/V),
// qb decode pairs heavy+light blocks per CU.
// ---------------------------------------------------------------------------
__global__ __launch_bounds__(256) void attn_kernel(
    const __bf16* __restrict__ q,   // [B][T][H]
    const __bf16* __restrict__ k,   // [B][T][H]
    const __bf16* __restrict__ vT,  // [B][H][T]
    float* __restrict__ out)        // [B][T][H] fp32
{
    __shared__ __bf16 KS[64 * 136];     // [krow][h], pad 8  (17.4 KB)
    __shared__ __bf16 VS[128 * 72];     // [h][t],    pad 8  (18.4 KB)
    __shared__ __bf16 PS[4][16 * 72];   // per-wave P [q][k], pad 8 (9.2 KB)

    const int L   = blockIdx.x;
    const int b   = L & 15;
    const int Lh  = L >> 4;
    const int qb  = (Lh < 16) ? (31 - Lh) : (Lh - 16);   // heavy first, CU-paired

    const int tid  = threadIdx.x;
    const int w    = tid >> 6;
    const int lane = tid & 63;
    const int m16  = lane & 15;
    const int quad = lane >> 4;
    const int koff = quad * 8;

    const __bf16* __restrict__ qp = q  + (long)b * T_ * H_;
    const __bf16* __restrict__ kp = k  + (long)b * T_ * H_;
    const __bf16* __restrict__ vp = vT + (long)b * H_ * T_;

    const int q0w = qb * 64 + w * 16;
    const int qg  = q0w + m16;

    bf16x8_t qfr[4];
    #pragma unroll
    for (int s = 0; s < 4; ++s)
        qfr[s] = *(const bf16x8_t*)&qp[(q0w + m16) * H_ + s * 32 + koff];

    f32x4_t acc[8];
    #pragma unroll
    for (int i = 0; i < 8; ++i) acc[i] = f32x4_t{0, 0, 0, 0};
    float mrun = -1e30f, lrun = 0.f;

    __bf16* Pb = &PS[w][0];
    const float SC = 0.08838834764831845f;   // 1/sqrt(128)
    const int kend = qb * 64 + 64;

    const int krow = tid >> 4, kc16 = tid & 15;   // K staging: 16 thr/row
    const int vrow = tid >> 3, vc8  = tid & 7;    // V staging: 8 thr/row

    // prologue: loads for tile 0 into registers
    bf16x8_t kr[4], vr[4];
    #pragma unroll
    for (int ch = 0; ch < 4; ++ch)
        kr[ch] = *(const bf16x8_t*)&kp[(krow + ch * 16) * H_ + kc16 * 8];
    #pragma unroll
    for (int ch = 0; ch < 4; ++ch)
        vr[ch] = *(const bf16x8_t*)&vp[(vrow + ch * 32) * (long)T_ + vc8 * 8];

    for (int tk0 = 0; tk0 < kend; tk0 += 64) {
        __syncthreads();                          // prev compute done with tiles
        #pragma unroll
        for (int ch = 0; ch < 4; ++ch)
            *(bf16x8_t*)&KS[(krow + ch * 16) * 136 + kc16 * 8] = kr[ch];
        #pragma unroll
        for (int ch = 0; ch < 4; ++ch)
            *(bf16x8_t*)&VS[(vrow + ch * 32) * 72 + vc8 * 8] = vr[ch];
        __syncthreads();                          // tiles ready

        // issue NEXT tile's loads now; they complete during the MFMAs below
        if (tk0 + 64 < kend) {
            #pragma unroll
            for (int ch = 0; ch < 4; ++ch)
                kr[ch] = *(const bf16x8_t*)&kp[(tk0 + 64 + krow + ch * 16) * H_ + kc16 * 8];
            #pragma unroll
            for (int ch = 0; ch < 4; ++ch)
                vr[ch] = *(const bf16x8_t*)&vp[(vrow + ch * 32) * (long)T_ + tk0 + 64 + vc8 * 8];
        }

        // ---- S^T = K Q^T : 4 S-tiles of 16 k-rows ----
        f32x4_t st[4];
        #pragma unroll
        for (int kt = 0; kt < 4; ++kt) {
            f32x4_t s = f32x4_t{0, 0, 0, 0};
            #pragma unroll
            for (int sI = 0; sI < 4; ++sI) {
                bf16x8_t kf = *(const bf16x8_t*)&KS[(kt * 16 + m16) * 136 + sI * 32 + koff];
                s = MFMA_16x16x32_BF16(kf, qfr[sI], s);
            }
            st[kt] = s;
        }

        // ---- scale (+ causal mask only on boundary tiles, wave-uniform) ----
        float vv[4][4];
        if (tk0 + 63 <= q0w) {
            #pragma unroll
            for (int kt = 0; kt < 4; ++kt)
                #pragma unroll
                for (int r = 0; r < 4; ++r)
                    vv[kt][r] = st[kt][r] * SC;
        } else {
            #pragma unroll
            for (int kt = 0; kt < 4; ++kt)
                #pragma unroll
                for (int r = 0; r < 4; ++r) {
                    int kg = tk0 + kt * 16 + quad * 4 + r;
                    vv[kt][r] = (kg <= qg) ? st[kt][r] * SC : -1e30f;
                }
        }

        float mloc = -1e30f;
        #pragma unroll
        for (int kt = 0; kt < 4; ++kt)
            #pragma unroll
            for (int r = 0; r < 4; ++r)
                mloc = fmaxf(mloc, vv[kt][r]);
        mloc = fmaxf(mloc, __shfl_xor(mloc, 16, 64));
        mloc = fmaxf(mloc, __shfl_xor(mloc, 32, 64));

        float mnew = fmaxf(mrun, mloc);
        float al   = __expf(mrun - mnew);
        float psum = 0.f;
        #pragma unroll
        for (int kt = 0; kt < 4; ++kt) {
            bf16x4_t pk;
            #pragma unroll
            for (int r = 0; r < 4; ++r) {
                float p = __expf(vv[kt][r] - mnew);
                psum += p;
                pk[r] = (__bf16)p;
            }
            *(bf16x4_t*)&Pb[m16 * 72 + kt * 16 + quad * 4] = pk;
        }
        psum += __shfl_xor(psum, 16, 64);
        psum += __shfl_xor(psum, 32, 64);
        mrun = mnew;
        lrun = lrun * al + psum;

        #pragma unroll
        for (int i = 0; i < 8; ++i)
            #pragma unroll
            for (int r = 0; r < 4; ++r)
                acc[i][r] *= al;

        // ---- O^T += V^T P^T : two K=32 halves ----
        #pragma unroll
        for (int half = 0; half < 2; ++half) {
            bf16x8_t pa = *(const bf16x8_t*)&Pb[m16 * 72 + half * 32 + koff];
            #pragma unroll
            for (int i = 0; i < 8; ++i) {
                bf16x8_t vf = *(const bf16x8_t*)&VS[(i * 16 + m16) * 72 + half * 32 + koff];
                acc[i] = MFMA_16x16x32_BF16(vf, pa, acc[i]);
            }
        }
    }

    // ---- epilogue ----
    float* __restrict__ ob = out + (long)b * T_ * H_;
    const float inv = 1.f / lrun;
    #pragma unroll
    for (int i = 0; i < 8; ++i) {
        f32x4_t o;
        #pragma unroll
        for (int r = 0; r < 4; ++r) o[r] = acc[i][r] * inv;
        *(f32x4_t*)&ob[(q0w + m16) * H_ + i * 16 + quad * 4] = o;
    }
}

// ---------------------------------------------------------------------------
extern "C" void kernel_launch(void* const* d_in, const int* in_sizes, int n_in,
                              void* d_out, int out_size, void* d_ws, size_t ws_size,
                              hipStream_t stream)
{
    // setup_inputs order: x, Wk, Wq, Wv — all float32
    const float* x  = (const float*)d_in[0];
    const float* Wk = (const float*)d_in[1];
    const float* Wq = (const float*)d_in[2];
    const float* Wv = (const float*)d_in[3];

    // ws: q [M,H] bf16 | k [M,H] bf16 | vT [B][H][T] bf16 | WT [3][H][C] bf16
    __bf16* qws = (__bf16*)d_ws;
    __bf16* kws = qws + M_ * H_;
    __bf16* vws = kws + M_ * H_;
    __bf16* WT  = vws + (long)B_ * H_ * T_;
    float*  out = (float*)d_out;

    wt_kernel  <<<dim3(C_ / 8, 3), 128, 0, stream>>>(Wq, Wk, Wv, WT);
    proj_kernel<<<dim3((int)(M_ / 32)), 256, 0, stream>>>(x, WT, qws, kws, vws);
    attn_kernel<<<dim3(512), 256, 0, stream>>>(qws, kws, vws, out);
}